// Round 8
// baseline (473.314 us; speedup 1.0000x reference)
//
#include <hip/hip_runtime.h>
#include <math.h>

#define N_NODES 100000
#define N_EDGES 200000
#define NNZ_    1600000
#define INC  128
#define OUTC 128
#define STAR_ 64
#define NEG 0.2f
#define NBIN_E 391  // ceil(200000/512)
#define NBIN_V 196  // ceil(100000/512)
#define NBIN (NBIN_E + NBIN_V)   // 587
#define CHUNK 4000  // 400 binA blocks x 4000 = NNZ exactly
#define NBLK_A (NNZ_/CHUNK)      // 400
#define NBLK_CVT 224             // (256*128 + 128*192)/256
#define CAP_E 5120  // padded E-bin capacity (mean 4092, +16 sigma)
#define CAP_V 9216  // padded V-bin capacity (mean 8163, +11 sigma)
#define PAIR_SZ (NBIN_E*CAP_E + NBIN_V*CAP_V)   // 3,808,256
#define CAPI 288    // k_edge staged incidence cap (16 edges, mean 128, +14 sigma)
#define CAPN 288    // k_node staged incidence cap (8 nodes, mean 128, +14 sigma)

typedef __attribute__((ext_vector_type(8))) short bf16x8_t;
typedef __attribute__((ext_vector_type(8))) unsigned short u16x8;
typedef __attribute__((ext_vector_type(4))) float f32x4_t;

__device__ __forceinline__ float leaky(float x){ return x > 0.f ? x : NEG*x; }
__device__ __forceinline__ float elu1(float x){ return x > 0.f ? x : __expf(x)-1.f; }
__device__ __forceinline__ unsigned short f2bf(float f){
  unsigned u = __float_as_uint(f);
  unsigned r = u + 0x7FFFu + ((u >> 16) & 1u);
  return (unsigned short)(r >> 16);
}
__device__ __forceinline__ float bf2f(unsigned short h){
  return __uint_as_float(((unsigned)h) << 16);
}
__device__ __forceinline__ int padBaseD(int bin){
  return bin < NBIN_E ? bin*CAP_E : NBIN_E*CAP_E + (bin-NBIN_E)*CAP_V;
}

// ---- k_cvtA: fusion of two INDEPENDENT stages ----
// blocks [0, NBLK_A)   : binA pair scatter (binCur = plain counts, memset-0 before)
// blocks [NBLK_A, +224): weight transpose/cvt + CSR tail zero pads
__global__ __launch_bounds__(256) void k_cvtA(
    const float* __restrict__ Wx, const float* __restrict__ Wv,
    const float* __restrict__ Wt,
    unsigned short* __restrict__ WcatT, unsigned short* __restrict__ WtT,
    const int* __restrict__ V, const int* __restrict__ E,
    int* __restrict__ binCur, int2* __restrict__ pair,
    int* __restrict__ vIdxE, int* __restrict__ eIdxV){
  __shared__ int hA[NBIN];
  __shared__ int baseA[NBIN];
  const int tid = threadIdx.x;

  if (blockIdx.x < NBLK_A) {
    for (int p = tid; p < NBIN; p += 256) hA[p] = 0;
    __syncthreads();
    const int start = blockIdx.x*CHUNK, end = start + CHUNK;
    for (int i = start + tid; i < end; i += 256){
      atomicAdd(&hA[E[i] >> 9], 1);
      atomicAdd(&hA[NBIN_E + (V[i] >> 9)], 1);
    }
    __syncthreads();
    for (int p = tid; p < NBIN; p += 256)
      baseA[p] = hA[p] ? padBaseD(p) + atomicAdd(&binCur[p], hA[p]) : 0;
    __syncthreads();
    for (int p = tid; p < NBIN; p += 256) hA[p] = 0;   // reuse as local cursor
    __syncthreads();
    for (int i = start + tid; i < end; i += 256){
      const int e = E[i], v = V[i];
      const int be = e >> 9, bv_ = NBIN_E + (v >> 9);
      const int se = baseA[be]  + atomicAdd(&hA[be],  1);
      const int sv = baseA[bv_] + atomicAdd(&hA[bv_], 1);
      pair[se] = make_int2(e, v);
      pair[sv] = make_int2(v, e);
    }
    return;
  }

  // ---- cvt: WcatT[256][128] = [Wx|Wv]^T bf16 ; WtT[128][192] = Wt^T bf16 ----
  const int i = (blockIdx.x - NBLK_A)*256 + tid;
  if (i < 256*128){
    const int n = i >> 7, k = i & 127;
    const float v = (n < 128) ? Wx[k*128 + n] : Wv[k*128 + (n-128)];
    WcatT[n*128 + k] = f2bf(v);
  }
  const int j = i - 256*128;
  if (j >= 0 && j < 128*192){
    const int n = j / 192, k = j - n*192;
    WtT[n*192 + k] = f2bf(Wt[k*128 + n]);
  }
  if (blockIdx.x == NBLK_A && tid < 16){
    vIdxE[NNZ_ + tid] = 0; eIdxV[NNZ_ + tid] = 0;
  }
}

// ---- k_front2: fusion of placement (depends on binA, prior kernel) with GEMM ----
// blocks [0, NBIN)        : binB fine placement (E-bins then V-bins), hidden under GEMM
// blocks [NBIN, NBIN+6250): GEMM1 + fused scoresExp = exp(leaky(Xfeat @ a))
__global__ __launch_bounds__(256) void k_front2(
    const float* __restrict__ X, const unsigned short* __restrict__ WcatT,
    const float* __restrict__ bx, const float* __restrict__ bv,
    const float* __restrict__ av,
    float* __restrict__ Xinit, unsigned short* __restrict__ Xfb,
    float* __restrict__ scoresExp,
    const int2* __restrict__ pair, const int* __restrict__ binCur,
    int* __restrict__ vIdxE, int* __restrict__ cntE, int* __restrict__ startsE,
    int* __restrict__ eIdxV, int* __restrict__ cntV, int* __restrict__ startsV){
  __shared__ __align__(16) char smem[6144];
  const int tid = threadIdx.x;

  if (blockIdx.x < NBIN) {
    // ---------------- binB: fine placement for one bin ----------------
    int* h   = (int*)smem;          // [512]
    int* sc0 = h + 512;             // [512]
    int* sc1 = sc0 + 512;           // [512]
    const int bin = blockIdx.x;
    const bool isE = bin < NBIN_E;
    const int nb = isE ? bin : bin - NBIN_E;
    const int bucket0 = nb << 9;
    const int nBuckTot = isE ? N_EDGES : N_NODES;
    const int pstart = padBaseD(bin);
    const int n = binCur[bin];      // count (binCur is count-mode)
    // self-compute itemBase = sum of counts of preceding bins
    {
      int part = 0;
      for (int p = tid; p < bin; p += 256) part += binCur[p];
      sc0[tid] = part;
      __syncthreads();
      for (int o = 128; o; o >>= 1){ if (tid < o) sc0[tid] += sc0[tid+o]; __syncthreads(); }
    }
    const int itemBase = isE ? sc0[0] : sc0[0] - NNZ_;
    __syncthreads();
    for (int p = tid; p < 512; p += 256) h[p] = 0;
    __syncthreads();
    for (int j = tid; j < n; j += 256) atomicAdd(&h[pair[pstart + j].x & 511], 1);
    __syncthreads();
    for (int p = tid; p < 512; p += 256) sc0[p] = h[p];
    __syncthreads();
    int* a = sc0; int* b = sc1;
    for (int o = 1; o < 512; o <<= 1){
      for (int p = tid; p < 512; p += 256) b[p] = a[p] + (p >= o ? a[p-o] : 0);
      __syncthreads();
      int* t = a; a = b; b = t;
    }
    for (int p = tid; p < 512; p += 256){
      const int excl = a[p] - h[p];
      b[p] = itemBase + excl;
      const int bucket = bucket0 + p;
      if (bucket < nBuckTot){
        if (isE){ cntE[bucket] = h[p]; startsE[bucket] = itemBase + excl; }
        else    { cntV[bucket] = h[p]; startsV[bucket] = itemBase + excl; }
      }
    }
    __syncthreads();
    for (int j = tid; j < n; j += 256){
      const int2 kv = pair[pstart + j];
      const int slot = atomicAdd(&b[kv.x & 511], 1);
      if (isE) vIdxE[slot] = kv.y; else eIdxV[slot] = kv.y;
    }
    return;
  }

  // ---------------- GEMM1 (MFMA) + fused scoresExp ----------------
  unsigned short (*xb)[136] = (unsigned short (*)[136])smem;   // 4352 B
  float* sc = (float*)(smem + 4352);                           // 64 B
  const int lane = tid & 63, w = tid >> 6;
  const int quad = lane >> 4, l16 = lane & 15;
  const int r0 = (blockIdx.x - NBIN) * 16;
  if (tid < 16) sc[tid] = 0.f;
  {
    const int r = tid >> 4;
    const int c0 = (tid & 15) * 8;
    const float4 a4 = *(const float4*)&X[(size_t)(r0+r)*INC + c0];
    const float4 b4 = *(const float4*)&X[(size_t)(r0+r)*INC + c0 + 4];
    bf16x8_t pk;
    pk[0]=(short)f2bf(a4.x); pk[1]=(short)f2bf(a4.y); pk[2]=(short)f2bf(a4.z); pk[3]=(short)f2bf(a4.w);
    pk[4]=(short)f2bf(b4.x); pk[5]=(short)f2bf(b4.y); pk[6]=(short)f2bf(b4.z); pk[7]=(short)f2bf(b4.w);
    *(bf16x8_t*)&xb[r][c0] = pk;
  }
  __syncthreads();
  f32x4_t acc[4] = {{0,0,0,0},{0,0,0,0},{0,0,0,0},{0,0,0,0}};
  const int n_base = w*64 + l16;
  for (int s = 0; s < 4; ++s){
    const bf16x8_t af = *(const bf16x8_t*)&xb[l16][s*32 + quad*8];
    #pragma unroll
    for (int nt = 0; nt < 4; ++nt){
      const int n = n_base + nt*16;
      const bf16x8_t bf = *(const bf16x8_t*)&WcatT[(size_t)n*128 + s*32 + quad*8];
      acc[nt] = __builtin_amdgcn_mfma_f32_16x16x32_bf16(af, bf, acc[nt], 0, 0, 0);
    }
  }
  float pr[4] = {0.f, 0.f, 0.f, 0.f};
  #pragma unroll
  for (int nt = 0; nt < 4; ++nt){
    const int n = n_base + nt*16;
    const float bias = (n < 128) ? bx[n] : bv[n-128];
    #pragma unroll
    for (int r = 0; r < 4; ++r){
      const int m = quad*4 + r;
      const float val = acc[nt][r] + bias;
      if (n < 128) Xinit[(size_t)(r0+m)*OUTC + n] = val;
      else {
        Xfb[(size_t)(r0+m)*OUTC + (n-128)] = f2bf(val);
        pr[r] += val * av[n-128];
      }
    }
  }
  if (w >= 2){
    #pragma unroll
    for (int r = 0; r < 4; ++r) atomicAdd(&sc[quad*4 + r], pr[r]);
  }
  __syncthreads();
  if (tid < 16) scoresExp[r0 + tid] = __expf(leaky(sc[tid]));
}

// ---- edge kernel (pure): weighted v2e aggregate + elu + MFMA [msg,S]@Wt + bt ----
// 16 lanes/edge, 16B/lane rows, unroll x8 (32 rows in flight/wave). Weight gathered
// from L2-resident scoresExp (broadcast within 16-lane group); denom in-register.
__global__ __launch_bounds__(256) void k_edge(
    const int* __restrict__ cntE, const int* __restrict__ startsE,
    const int* __restrict__ vIdxE, const float* __restrict__ scoresExp,
    const unsigned short* __restrict__ Xfb,
    const float* __restrict__ S, const unsigned short* __restrict__ WtT,
    const float* __restrict__ bt, unsigned short* __restrict__ Ybf) {
  __shared__ int inc[CAPI + 8];
  __shared__ unsigned short msg[16][200];
  const int tid = threadIdx.x;
  const int lane = tid & 63, w = tid >> 6;
  const int e0 = blockIdx.x * 16;
  const int g16 = tid >> 4, s16 = tid & 15;

  const int st0 = startsE[e0];
  const int lim = startsE[e0 + 15] + cntE[e0 + 15] - st0;

  for (int i = tid; i < CAPI + 8; i += 256)
    inc[i] = (i < lim) ? vIdxE[st0 + i] : 0;

  {
    const float4 s4 = *(const float4*)&S[(size_t)(e0+g16)*STAR_ + s16*4];
    ushort4 pk; pk.x=f2bf(s4.x); pk.y=f2bf(s4.y); pk.z=f2bf(s4.z); pk.w=f2bf(s4.w);
    *(ushort4*)&msg[g16][128 + s16*4] = pk;
  }
  __syncthreads();

  const int e = e0 + g16;
  const int deg = cntE[e];
  const int lo  = startsE[e] - st0;
  const int c8 = s16 * 8;
  float ac[8] = {0.f,0.f,0.f,0.f,0.f,0.f,0.f,0.f};
  float wsum = 0.f;
  if (lo + deg <= CAPI) {               // statistically always
    for (int j = 0; j < deg; j += 8) {
      int pp[8];
      #pragma unroll
      for (int k = 0; k < 8; ++k) pp[k] = inc[lo + j + k];
      float ww[8];
      #pragma unroll
      for (int k = 0; k < 8; ++k) ww[k] = scoresExp[pp[k]];
      u16x8 xx[8];
      #pragma unroll
      for (int k = 0; k < 8; ++k)
        xx[k] = *(const u16x8*)&Xfb[(size_t)pp[k]*OUTC + c8];
      #pragma unroll
      for (int k = 0; k < 8; ++k) {
        const float wgt = (j + k < deg) ? ww[k] : 0.f;
        wsum += wgt;
        #pragma unroll
        for (int q = 0; q < 8; ++q) ac[q] += wgt * bf2f(xx[k][q]);
      }
    }
  } else {                              // rare overflow: direct global
    const int st = st0 + lo;
    for (int j = 0; j < deg; j += 8) {
      int pp[8];
      #pragma unroll
      for (int k = 0; k < 8; ++k) pp[k] = vIdxE[st + j + k];
      float ww[8];
      #pragma unroll
      for (int k = 0; k < 8; ++k) ww[k] = scoresExp[pp[k]];
      u16x8 xx[8];
      #pragma unroll
      for (int k = 0; k < 8; ++k)
        xx[k] = *(const u16x8*)&Xfb[(size_t)pp[k]*OUTC + c8];
      #pragma unroll
      for (int k = 0; k < 8; ++k) {
        const float wgt = (j + k < deg) ? ww[k] : 0.f;
        wsum += wgt;
        #pragma unroll
        for (int q = 0; q < 8; ++q) ac[q] += wgt * bf2f(xx[k][q]);
      }
    }
  }
  {
    const float invd = wsum > 0.f ? 1.f/wsum : 0.f;
    u16x8 pk;
    #pragma unroll
    for (int q = 0; q < 8; ++q) pk[q] = f2bf(elu1(ac[q]*invd));
    *(u16x8*)&msg[g16][c8] = pk;
  }
  __syncthreads();

  const int quad = lane >> 4, l16 = lane & 15;
  f32x4_t acc0 = {0,0,0,0}, acc1 = {0,0,0,0};
  const int n0 = w * 32;
  for (int s = 0; s < 6; ++s) {
    const bf16x8_t af = *(const bf16x8_t*)&msg[l16][s*32 + quad*8];
    const bf16x8_t b0 = *(const bf16x8_t*)&WtT[(size_t)(n0 + l16)*192      + s*32 + quad*8];
    const bf16x8_t b1 = *(const bf16x8_t*)&WtT[(size_t)(n0 + 16 + l16)*192 + s*32 + quad*8];
    acc0 = __builtin_amdgcn_mfma_f32_16x16x32_bf16(af, b0, acc0, 0, 0, 0);
    acc1 = __builtin_amdgcn_mfma_f32_16x16x32_bf16(af, b1, acc1, 0, 0, 0);
  }
  const float bt0 = bt[n0 + l16], bt1 = bt[n0 + 16 + l16];
  #pragma unroll
  for (int r = 0; r < 4; ++r) {
    const int m = quad*4 + r;
    Ybf[(size_t)(e0+m)*OUTC + n0 + l16]      = f2bf(acc0[r] + bt0);
    Ybf[(size_t)(e0+m)*OUTC + n0 + 16 + l16] = f2bf(acc1[r] + bt1);
  }
}

// ---- node kernel: scatter-mean(Y[E]) by V, elu, + X_init ----
// 8 nodes/block, 32 lanes x 8B per row, unroll x8, LDS-staged eIdxV slice.
__global__ __launch_bounds__(256) void k_node(
    const int* __restrict__ cntV, const int* __restrict__ startsV,
    const int* __restrict__ eIdxV,
    const unsigned short* __restrict__ Ybf, float* __restrict__ out) {
  __shared__ int elds[CAPN + 8];
  const int tid = threadIdx.x;
  const int sub = tid & 31, grp = tid >> 5;
  const int v0 = blockIdx.x * 8;

  const int st0 = startsV[v0];
  const int lim = startsV[v0 + 7] + cntV[v0 + 7] - st0;
  for (int i = tid; i < CAPN + 8; i += 256)
    elds[i] = (i < lim) ? eIdxV[st0 + i] : 0;
  __syncthreads();

  const int v = v0 + grp;
  const int c4 = sub * 4;
  const int deg = cntV[v];
  const int lo  = startsV[v] - st0;
  float a0=0.f, a1=0.f, a2=0.f, a3=0.f;
  if (lo + deg <= CAPN) {
    for (int j = 0; j < deg; j += 8) {
      int ee[8];
      #pragma unroll
      for (int k = 0; k < 8; ++k) ee[k] = elds[lo + j + k];
      ushort4 yy[8];
      #pragma unroll
      for (int k = 0; k < 8; ++k)
        yy[k] = *(const ushort4*)&Ybf[(size_t)ee[k]*OUTC + c4];
      #pragma unroll
      for (int k = 0; k < 8; ++k) {
        const float pz = (j + k < deg) ? 1.f : 0.f;
        a0 += pz * bf2f(yy[k].x); a1 += pz * bf2f(yy[k].y);
        a2 += pz * bf2f(yy[k].z); a3 += pz * bf2f(yy[k].w);
      }
    }
  } else {
    const int st = st0 + lo;
    for (int j = 0; j < deg; j += 8) {
      int ee[8];
      #pragma unroll
      for (int k = 0; k < 8; ++k) ee[k] = eIdxV[st + j + k];
      ushort4 yy[8];
      #pragma unroll
      for (int k = 0; k < 8; ++k)
        yy[k] = *(const ushort4*)&Ybf[(size_t)ee[k]*OUTC + c4];
      #pragma unroll
      for (int k = 0; k < 8; ++k) {
        const float pz = (j + k < deg) ? 1.f : 0.f;
        a0 += pz * bf2f(yy[k].x); a1 += pz * bf2f(yy[k].y);
        a2 += pz * bf2f(yy[k].z); a3 += pz * bf2f(yy[k].w);
      }
    }
  }
  const float invd = 1.f / fmaxf((float)deg, 1.f);
  float4 o = *(float4*)&out[(size_t)v*OUTC + c4];
  o.x = elu1(a0*invd) + o.x;
  o.y = elu1(a1*invd) + o.y;
  o.z = elu1(a2*invd) + o.z;
  o.w = elu1(a3*invd) + o.w;
  *(float4*)&out[(size_t)v*OUTC + c4] = o;
}

extern "C" void kernel_launch(void* const* d_in, const int* in_sizes, int n_in,
                              void* d_out, int out_size, void* d_ws, size_t ws_size,
                              hipStream_t stream) {
  const float* X  = (const float*)d_in[0];
  const int*   V  = (const int*)d_in[1];
  const int*   E  = (const int*)d_in[2];
  const float* S  = (const float*)d_in[3];
  const float* Wx = (const float*)d_in[4];
  const float* bx = (const float*)d_in[5];
  const float* Wv = (const float*)d_in[6];
  const float* bv = (const float*)d_in[7];
  const float* av = (const float*)d_in[8];
  const float* Wt = (const float*)d_in[9];
  const float* bt = (const float*)d_in[10];
  float* out = (float*)d_out;

  char* ws = (char*)d_ws;
  size_t off = 0;
  auto alloc = [&](size_t bytes) -> void* {
    off = (off + 255) & ~(size_t)255;
    void* p = ws + off; off += bytes; return p;
  };
  unsigned short* Xfb   = (unsigned short*)alloc((size_t)N_NODES*OUTC*2);
  unsigned short* Ybf   = (unsigned short*)alloc((size_t)N_EDGES*OUTC*2);
  float* scoresExp = (float*)alloc((size_t)N_NODES*4);
  unsigned short* WcatT = (unsigned short*)alloc((size_t)256*128*2);
  unsigned short* WtT   = (unsigned short*)alloc((size_t)128*192*2);
  int2* pair   = (int2*)alloc((size_t)PAIR_SZ*8);      // 30.5 MB padded bins
  int* binCur  = (int*)alloc((size_t)NBIN*4);
  int* cntE    = (int*)alloc((size_t)N_EDGES*4);
  int* cntV    = (int*)alloc((size_t)N_NODES*4);
  int* startsE = (int*)alloc((size_t)N_EDGES*4);
  int* startsV = (int*)alloc((size_t)N_NODES*4);
  int* vIdxE   = (int*)alloc((size_t)(NNZ_+16)*4);
  int* eIdxV   = (int*)alloc((size_t)(NNZ_+16)*4);

  hipMemsetAsync(binCur, 0, (size_t)NBIN*4, stream);
  k_cvtA<<<NBLK_A + NBLK_CVT, 256, 0, stream>>>(Wx, Wv, Wt, WcatT, WtT,
                                                V, E, binCur, pair, vIdxE, eIdxV);
  k_front2<<<NBIN + N_NODES/16, 256, 0, stream>>>(X, WcatT, bx, bv, av, out, Xfb, scoresExp,
                                                  pair, binCur,
                                                  vIdxE, cntE, startsE,
                                                  eIdxV, cntV, startsV);
  k_edge<<<N_EDGES/16, 256, 0, stream>>>(cntE, startsE, vIdxE, scoresExp,
                                         Xfb, S, WtT, bt, Ybf);
  k_node<<<N_NODES/8, 256, 0, stream>>>(cntV, startsV, eIdxV, Ybf, out);
}

// Round 9
// 462.513 us; speedup vs baseline: 1.0234x; 1.0234x over previous
//
#include <hip/hip_runtime.h>
#include <math.h>

#define N_NODES 100000
#define N_EDGES 200000
#define NNZ_    1600000
#define INC  128
#define OUTC 128
#define STAR_ 64
#define NEG 0.2f
#define NBIN_E 391  // ceil(200000/512)
#define NBIN_V 196  // ceil(100000/512)
#define NBIN (NBIN_E + NBIN_V)   // 587
#define CHUNK 4000  // 400 binA blocks x 4000 = NNZ exactly
#define NBLK_A (NNZ_/CHUNK)      // 400
#define CAP_E 5120  // padded E-bin capacity (mean 4092, +16 sigma)
#define CAP_V 9216  // padded V-bin capacity (mean 8163, +11 sigma)
#define PAIR_SZ (NBIN_E*CAP_E + NBIN_V*CAP_V)   // 3,808,256
#define CAPI 288    // k_edge staged incidence cap (16 edges, mean 128, +14 sigma)
#define CAPN 288    // k_node staged incidence cap (8 nodes, mean 128, +14 sigma)

typedef __attribute__((ext_vector_type(8))) short bf16x8_t;
typedef __attribute__((ext_vector_type(8))) unsigned short u16x8;
typedef __attribute__((ext_vector_type(4))) float f32x4_t;

__device__ __forceinline__ float leaky(float x){ return x > 0.f ? x : NEG*x; }
__device__ __forceinline__ float elu1(float x){ return x > 0.f ? x : __expf(x)-1.f; }
__device__ __forceinline__ unsigned short f2bf(float f){
  unsigned u = __float_as_uint(f);
  unsigned r = u + 0x7FFFu + ((u >> 16) & 1u);
  return (unsigned short)(r >> 16);
}
__device__ __forceinline__ float bf2f(unsigned short h){
  return __uint_as_float(((unsigned)h) << 16);
}
__device__ __forceinline__ int padBaseD(int bin){
  return bin < NBIN_E ? bin*CAP_E : NBIN_E*CAP_E + (bin-NBIN_E)*CAP_V;
}

// ---- cvt: WcatT[256][128] = [Wx|Wv]^T bf16 ; WtT[128][192] = Wt^T bf16 ----
// Block 0: binCur init (cursor mode) + CSR-tail zero pads.
__global__ void k_cvt(const float* __restrict__ Wx, const float* __restrict__ Wv,
                      const float* __restrict__ Wt,
                      unsigned short* __restrict__ WcatT, unsigned short* __restrict__ WtT,
                      int* __restrict__ binCur,
                      int* __restrict__ vIdxE, int* __restrict__ eIdxV){
  const int i = blockIdx.x*256 + threadIdx.x;
  if (i < 256*128){
    const int n = i >> 7, k = i & 127;
    const float v = (n < 128) ? Wx[k*128 + n] : Wv[k*128 + (n-128)];
    WcatT[n*128 + k] = f2bf(v);
  }
  const int j = i - 256*128;
  if (j >= 0 && j < 128*192){
    const int n = j / 192, k = j - n*192;
    WtT[n*192 + k] = f2bf(Wt[k*128 + n]);
  }
  if (blockIdx.x == 0){
    for (int p = threadIdx.x; p < NBIN; p += 256) binCur[p] = padBaseD(p);
    if (threadIdx.x < 16){ vIdxE[NNZ_ + threadIdx.x] = 0; eIdxV[NNZ_ + threadIdx.x] = 0; }
  }
}

// ---- k_front: grid-partitioned fusion of two INDEPENDENT kernels ----
// blocks [0, NBLK_A)           : binA pair scatter (hides under the GEMM blocks)
// blocks [NBLK_A, NBLK_A+6250) : GEMM1 + fused scoresExp = exp(leaky(Xfeat @ a))
__global__ __launch_bounds__(256) void k_front(
    const float* __restrict__ X, const unsigned short* __restrict__ WcatT,
    const float* __restrict__ bx, const float* __restrict__ bv,
    const float* __restrict__ av,
    float* __restrict__ Xinit, unsigned short* __restrict__ Xfb,
    float* __restrict__ scoresExp,
    const int* __restrict__ V, const int* __restrict__ E,
    int* __restrict__ binCur, int2* __restrict__ pair){
  __shared__ int hA[NBIN];
  __shared__ int baseA[NBIN];
  __shared__ unsigned short xb[16][136];
  __shared__ float sc[16];
  const int tid = threadIdx.x;

  if (blockIdx.x < NBLK_A) {
    for (int p = tid; p < NBIN; p += 256) hA[p] = 0;
    __syncthreads();
    const int start = blockIdx.x*CHUNK, end = start + CHUNK;
    for (int i = start + tid; i < end; i += 256){
      atomicAdd(&hA[E[i] >> 9], 1);
      atomicAdd(&hA[NBIN_E + (V[i] >> 9)], 1);
    }
    __syncthreads();
    for (int p = tid; p < NBIN; p += 256)
      baseA[p] = hA[p] ? atomicAdd(&binCur[p], hA[p]) : 0;
    __syncthreads();
    for (int p = tid; p < NBIN; p += 256) hA[p] = 0;   // reuse as local cursor
    __syncthreads();
    for (int i = start + tid; i < end; i += 256){
      const int e = E[i], v = V[i];
      const int be = e >> 9, bv_ = NBIN_E + (v >> 9);
      const int se = baseA[be]  + atomicAdd(&hA[be],  1);
      const int sv = baseA[bv_] + atomicAdd(&hA[bv_], 1);
      pair[se] = make_int2(e, v);
      pair[sv] = make_int2(v, e);
    }
    return;
  }

  // ---------------- GEMM1 (MFMA) + fused scoresExp ----------------
  const int lane = tid & 63, w = tid >> 6;
  const int quad = lane >> 4, l16 = lane & 15;
  const int r0 = (blockIdx.x - NBLK_A) * 16;
  if (tid < 16) sc[tid] = 0.f;
  {
    const int r = tid >> 4;
    const int c0 = (tid & 15) * 8;
    const float4 a4 = *(const float4*)&X[(size_t)(r0+r)*INC + c0];
    const float4 b4 = *(const float4*)&X[(size_t)(r0+r)*INC + c0 + 4];
    bf16x8_t pk;
    pk[0]=(short)f2bf(a4.x); pk[1]=(short)f2bf(a4.y); pk[2]=(short)f2bf(a4.z); pk[3]=(short)f2bf(a4.w);
    pk[4]=(short)f2bf(b4.x); pk[5]=(short)f2bf(b4.y); pk[6]=(short)f2bf(b4.z); pk[7]=(short)f2bf(b4.w);
    *(bf16x8_t*)&xb[r][c0] = pk;
  }
  __syncthreads();
  f32x4_t acc[4] = {{0,0,0,0},{0,0,0,0},{0,0,0,0},{0,0,0,0}};
  const int n_base = w*64 + l16;
  for (int s = 0; s < 4; ++s){
    const bf16x8_t af = *(const bf16x8_t*)&xb[l16][s*32 + quad*8];
    #pragma unroll
    for (int nt = 0; nt < 4; ++nt){
      const int n = n_base + nt*16;
      const bf16x8_t bf = *(const bf16x8_t*)&WcatT[(size_t)n*128 + s*32 + quad*8];
      acc[nt] = __builtin_amdgcn_mfma_f32_16x16x32_bf16(af, bf, acc[nt], 0, 0, 0);
    }
  }
  float pr[4] = {0.f, 0.f, 0.f, 0.f};
  #pragma unroll
  for (int nt = 0; nt < 4; ++nt){
    const int n = n_base + nt*16;
    const float bias = (n < 128) ? bx[n] : bv[n-128];
    #pragma unroll
    for (int r = 0; r < 4; ++r){
      const int m = quad*4 + r;
      const float val = acc[nt][r] + bias;
      if (n < 128) Xinit[(size_t)(r0+m)*OUTC + n] = val;
      else {
        Xfb[(size_t)(r0+m)*OUTC + (n-128)] = f2bf(val);
        pr[r] += val * av[n-128];
      }
    }
  }
  if (w >= 2){
    #pragma unroll
    for (int r = 0; r < 4; ++r) atomicAdd(&sc[quad*4 + r], pr[r]);
  }
  __syncthreads();
  if (tid < 16) scoresExp[r0 + tid] = __expf(leaky(sc[tid]));
}

// ---- k_binB: pure placement for ALL bins (E then V), 512 threads/block.
// Self-computes itemBase via reduction over binCur (cursor mode: count = cur - padBase).
__global__ __launch_bounds__(512) void k_binB(const int2* __restrict__ pair,
    const int* __restrict__ binCur,
    int* __restrict__ vIdxE, int* __restrict__ cntE, int* __restrict__ startsE,
    int* __restrict__ eIdxV, int* __restrict__ cntV, int* __restrict__ startsV){
  __shared__ int h[512], sc0[512], sc1[512];
  const int bin = blockIdx.x;
  const bool isE = bin < NBIN_E;
  const int nb = isE ? bin : bin - NBIN_E;
  const int bucket0 = nb << 9;
  const int nBuckTot = isE ? N_EDGES : N_NODES;
  const int pstart = padBaseD(bin);
  const int n = binCur[bin] - pstart;
  const int tid = threadIdx.x;
  // itemBase = sum of counts of preceding bins (V bins: shift out the NNZ_ E-items)
  {
    int part = 0;
    for (int p = tid; p < bin; p += 512) part += binCur[p] - padBaseD(p);
    sc0[tid] = part;
    __syncthreads();
    for (int o = 256; o; o >>= 1){ if (tid < o) sc0[tid] += sc0[tid+o]; __syncthreads(); }
  }
  const int itemBase = sc0[0] - (isE ? 0 : NNZ_);
  __syncthreads();
  h[tid] = 0;
  __syncthreads();
  for (int j = tid; j < n; j += 512) atomicAdd(&h[pair[pstart + j].x & 511], 1);
  __syncthreads();
  sc0[tid] = h[tid];
  __syncthreads();
  int* a = sc0; int* b = sc1;
  for (int o = 1; o < 512; o <<= 1){
    b[tid] = a[tid] + (tid >= o ? a[tid-o] : 0);
    __syncthreads();
    int* t = a; a = b; b = t;
  }
  {
    const int excl = a[tid] - h[tid];
    b[tid] = itemBase + excl;
    const int bucket = bucket0 + tid;
    if (bucket < nBuckTot){
      if (isE){ cntE[bucket] = h[tid]; startsE[bucket] = itemBase + excl; }
      else    { cntV[bucket] = h[tid]; startsV[bucket] = itemBase + excl; }
    }
  }
  __syncthreads();
  for (int j = tid; j < n; j += 512){
    const int2 kv = pair[pstart + j];
    const int slot = atomicAdd(&b[kv.x & 511], 1);
    if (isE) vIdxE[slot] = kv.y; else eIdxV[slot] = kv.y;
  }
}

// ---- edge kernel (pure): weighted v2e aggregate + elu + MFMA [msg,S]@Wt + bt ----
// 16 lanes/edge, 16B/lane rows, unroll x8 (32 rows in flight/wave). Weight gathered
// from L2-resident scoresExp (broadcast within 16-lane group); denom in-register.
__global__ __launch_bounds__(256) void k_edge(
    const int* __restrict__ cntE, const int* __restrict__ startsE,
    const int* __restrict__ vIdxE, const float* __restrict__ scoresExp,
    const unsigned short* __restrict__ Xfb,
    const float* __restrict__ S, const unsigned short* __restrict__ WtT,
    const float* __restrict__ bt, unsigned short* __restrict__ Ybf) {
  __shared__ int inc[CAPI + 8];
  __shared__ unsigned short msg[16][200];
  const int tid = threadIdx.x;
  const int lane = tid & 63, w = tid >> 6;
  const int e0 = blockIdx.x * 16;
  const int g16 = tid >> 4, s16 = tid & 15;

  const int st0 = startsE[e0];
  const int lim = startsE[e0 + 15] + cntE[e0 + 15] - st0;

  for (int i = tid; i < CAPI + 8; i += 256)
    inc[i] = (i < lim) ? vIdxE[st0 + i] : 0;

  {
    const float4 s4 = *(const float4*)&S[(size_t)(e0+g16)*STAR_ + s16*4];
    ushort4 pk; pk.x=f2bf(s4.x); pk.y=f2bf(s4.y); pk.z=f2bf(s4.z); pk.w=f2bf(s4.w);
    *(ushort4*)&msg[g16][128 + s16*4] = pk;
  }
  __syncthreads();

  const int e = e0 + g16;
  const int deg = cntE[e];
  const int lo  = startsE[e] - st0;
  const int c8 = s16 * 8;
  float ac[8] = {0.f,0.f,0.f,0.f,0.f,0.f,0.f,0.f};
  float wsum = 0.f;
  if (lo + deg <= CAPI) {               // statistically always
    for (int j = 0; j < deg; j += 8) {
      int pp[8];
      #pragma unroll
      for (int k = 0; k < 8; ++k) pp[k] = inc[lo + j + k];
      float ww[8];
      #pragma unroll
      for (int k = 0; k < 8; ++k) ww[k] = scoresExp[pp[k]];
      u16x8 xx[8];
      #pragma unroll
      for (int k = 0; k < 8; ++k)
        xx[k] = *(const u16x8*)&Xfb[(size_t)pp[k]*OUTC + c8];
      #pragma unroll
      for (int k = 0; k < 8; ++k) {
        const float wgt = (j + k < deg) ? ww[k] : 0.f;
        wsum += wgt;
        #pragma unroll
        for (int q = 0; q < 8; ++q) ac[q] += wgt * bf2f(xx[k][q]);
      }
    }
  } else {                              // rare overflow: direct global
    const int st = st0 + lo;
    for (int j = 0; j < deg; j += 8) {
      int pp[8];
      #pragma unroll
      for (int k = 0; k < 8; ++k) pp[k] = vIdxE[st + j + k];
      float ww[8];
      #pragma unroll
      for (int k = 0; k < 8; ++k) ww[k] = scoresExp[pp[k]];
      u16x8 xx[8];
      #pragma unroll
      for (int k = 0; k < 8; ++k)
        xx[k] = *(const u16x8*)&Xfb[(size_t)pp[k]*OUTC + c8];
      #pragma unroll
      for (int k = 0; k < 8; ++k) {
        const float wgt = (j + k < deg) ? ww[k] : 0.f;
        wsum += wgt;
        #pragma unroll
        for (int q = 0; q < 8; ++q) ac[q] += wgt * bf2f(xx[k][q]);
      }
    }
  }
  {
    const float invd = wsum > 0.f ? 1.f/wsum : 0.f;
    u16x8 pk;
    #pragma unroll
    for (int q = 0; q < 8; ++q) pk[q] = f2bf(elu1(ac[q]*invd));
    *(u16x8*)&msg[g16][c8] = pk;
  }
  __syncthreads();

  const int quad = lane >> 4, l16 = lane & 15;
  f32x4_t acc0 = {0,0,0,0}, acc1 = {0,0,0,0};
  const int n0 = w * 32;
  for (int s = 0; s < 6; ++s) {
    const bf16x8_t af = *(const bf16x8_t*)&msg[l16][s*32 + quad*8];
    const bf16x8_t b0 = *(const bf16x8_t*)&WtT[(size_t)(n0 + l16)*192      + s*32 + quad*8];
    const bf16x8_t b1 = *(const bf16x8_t*)&WtT[(size_t)(n0 + 16 + l16)*192 + s*32 + quad*8];
    acc0 = __builtin_amdgcn_mfma_f32_16x16x32_bf16(af, b0, acc0, 0, 0, 0);
    acc1 = __builtin_amdgcn_mfma_f32_16x16x32_bf16(af, b1, acc1, 0, 0, 0);
  }
  const float bt0 = bt[n0 + l16], bt1 = bt[n0 + 16 + l16];
  #pragma unroll
  for (int r = 0; r < 4; ++r) {
    const int m = quad*4 + r;
    Ybf[(size_t)(e0+m)*OUTC + n0 + l16]      = f2bf(acc0[r] + bt0);
    Ybf[(size_t)(e0+m)*OUTC + n0 + 16 + l16] = f2bf(acc1[r] + bt1);
  }
}

// ---- node kernel: scatter-mean(Y[E]) by V, elu, + X_init ----
// 8 nodes/block, 32 lanes x 8B per row, unroll x8, LDS-staged eIdxV slice.
__global__ __launch_bounds__(256) void k_node(
    const int* __restrict__ cntV, const int* __restrict__ startsV,
    const int* __restrict__ eIdxV,
    const unsigned short* __restrict__ Ybf, float* __restrict__ out) {
  __shared__ int elds[CAPN + 8];
  const int tid = threadIdx.x;
  const int sub = tid & 31, grp = tid >> 5;
  const int v0 = blockIdx.x * 8;

  const int st0 = startsV[v0];
  const int lim = startsV[v0 + 7] + cntV[v0 + 7] - st0;
  for (int i = tid; i < CAPN + 8; i += 256)
    elds[i] = (i < lim) ? eIdxV[st0 + i] : 0;
  __syncthreads();

  const int v = v0 + grp;
  const int c4 = sub * 4;
  const int deg = cntV[v];
  const int lo  = startsV[v] - st0;
  float a0=0.f, a1=0.f, a2=0.f, a3=0.f;
  if (lo + deg <= CAPN) {
    for (int j = 0; j < deg; j += 8) {
      int ee[8];
      #pragma unroll
      for (int k = 0; k < 8; ++k) ee[k] = elds[lo + j + k];
      ushort4 yy[8];
      #pragma unroll
      for (int k = 0; k < 8; ++k)
        yy[k] = *(const ushort4*)&Ybf[(size_t)ee[k]*OUTC + c4];
      #pragma unroll
      for (int k = 0; k < 8; ++k) {
        const float pz = (j + k < deg) ? 1.f : 0.f;
        a0 += pz * bf2f(yy[k].x); a1 += pz * bf2f(yy[k].y);
        a2 += pz * bf2f(yy[k].z); a3 += pz * bf2f(yy[k].w);
      }
    }
  } else {
    const int st = st0 + lo;
    for (int j = 0; j < deg; j += 8) {
      int ee[8];
      #pragma unroll
      for (int k = 0; k < 8; ++k) ee[k] = eIdxV[st + j + k];
      ushort4 yy[8];
      #pragma unroll
      for (int k = 0; k < 8; ++k)
        yy[k] = *(const ushort4*)&Ybf[(size_t)ee[k]*OUTC + c4];
      #pragma unroll
      for (int k = 0; k < 8; ++k) {
        const float pz = (j + k < deg) ? 1.f : 0.f;
        a0 += pz * bf2f(yy[k].x); a1 += pz * bf2f(yy[k].y);
        a2 += pz * bf2f(yy[k].z); a3 += pz * bf2f(yy[k].w);
      }
    }
  }
  const float invd = 1.f / fmaxf((float)deg, 1.f);
  float4 o = *(float4*)&out[(size_t)v*OUTC + c4];
  o.x = elu1(a0*invd) + o.x;
  o.y = elu1(a1*invd) + o.y;
  o.z = elu1(a2*invd) + o.z;
  o.w = elu1(a3*invd) + o.w;
  *(float4*)&out[(size_t)v*OUTC + c4] = o;
}

extern "C" void kernel_launch(void* const* d_in, const int* in_sizes, int n_in,
                              void* d_out, int out_size, void* d_ws, size_t ws_size,
                              hipStream_t stream) {
  const float* X  = (const float*)d_in[0];
  const int*   V  = (const int*)d_in[1];
  const int*   E  = (const int*)d_in[2];
  const float* S  = (const float*)d_in[3];
  const float* Wx = (const float*)d_in[4];
  const float* bx = (const float*)d_in[5];
  const float* Wv = (const float*)d_in[6];
  const float* bv = (const float*)d_in[7];
  const float* av = (const float*)d_in[8];
  const float* Wt = (const float*)d_in[9];
  const float* bt = (const float*)d_in[10];
  float* out = (float*)d_out;

  char* ws = (char*)d_ws;
  size_t off = 0;
  auto alloc = [&](size_t bytes) -> void* {
    off = (off + 255) & ~(size_t)255;
    void* p = ws + off; off += bytes; return p;
  };
  unsigned short* Xfb   = (unsigned short*)alloc((size_t)N_NODES*OUTC*2);
  unsigned short* Ybf   = (unsigned short*)alloc((size_t)N_EDGES*OUTC*2);
  float* scoresExp = (float*)alloc((size_t)N_NODES*4);
  unsigned short* WcatT = (unsigned short*)alloc((size_t)256*128*2);
  unsigned short* WtT   = (unsigned short*)alloc((size_t)128*192*2);
  int2* pair   = (int2*)alloc((size_t)PAIR_SZ*8);      // 30.5 MB padded bins
  int* binCur  = (int*)alloc((size_t)NBIN*4);
  int* cntE    = (int*)alloc((size_t)N_EDGES*4);
  int* cntV    = (int*)alloc((size_t)N_NODES*4);
  int* startsE = (int*)alloc((size_t)N_EDGES*4);
  int* startsV = (int*)alloc((size_t)N_NODES*4);
  int* vIdxE   = (int*)alloc((size_t)(NNZ_+16)*4);
  int* eIdxV   = (int*)alloc((size_t)(NNZ_+16)*4);

  k_cvt<<<(256*128 + 128*192 + 255)/256, 256, 0, stream>>>(Wx, Wv, Wt, WcatT, WtT,
                                                           binCur, vIdxE, eIdxV);
  k_front<<<NBLK_A + N_NODES/16, 256, 0, stream>>>(X, WcatT, bx, bv, av, out, Xfb, scoresExp,
                                                   V, E, binCur, pair);
  k_binB<<<NBIN, 512, 0, stream>>>(pair, binCur,
                                   vIdxE, cntE, startsE,
                                   eIdxV, cntV, startsV);
  k_edge<<<N_EDGES/16, 256, 0, stream>>>(cntE, startsE, vIdxE, scoresExp,
                                         Xfb, S, WtT, bt, Ybf);
  k_node<<<N_NODES/8, 256, 0, stream>>>(cntV, startsV, eIdxV, Ybf, out);
}